// Round 2
// baseline (182.952 us; speedup 1.0000x reference)
//
#include <hip/hip_runtime.h>
#include <hip/hip_bf16.h>

// Problem constants
#define BB 8
#define TT 2048
#define EE 1024
#define HH 64

typedef __attribute__((ext_vector_type(8))) short short8;
typedef __attribute__((ext_vector_type(4))) float f32x4;

__device__ inline f32x4 mfma_16x16x32(short8 a, short8 b, f32x4 c) {
  return __builtin_amdgcn_mfma_f32_16x16x32_bf16(a, b, c, 0, 0, 0);
}

// async global->LDS, 16B per lane, LDS dest = wave-uniform base + lane*16
__device__ inline void gload_lds16(const __hip_bfloat16* g, __hip_bfloat16* l) {
  __builtin_amdgcn_global_load_lds((const __attribute__((address_space(1))) void*)g,
                                   (__attribute__((address_space(3))) void*)l,
                                   16, 0, 0);
}

__device__ inline short f2bf(float f) {
  __hip_bfloat16 h = __float2bfloat16(f);
  return *reinterpret_cast<short*>(&h);
}
__device__ inline float bf2f(short s) {
  __hip_bfloat16 h = *reinterpret_cast<__hip_bfloat16*>(&s);
  return __bfloat162float(h);
}

// wait lgkmcnt(0) only; leave vmcnt/expcnt unconstrained
#define WAIT_LGKM0() __builtin_amdgcn_s_waitcnt(0xC07F)

// ---------------------------------------------------------------------------
// Kernel 0: split-precision transposed weights (unchanged).
// ---------------------------------------------------------------------------
__global__ void prep_w(const float* __restrict__ Wq, const float* __restrict__ Wk,
                       const float* __restrict__ Wv,
                       __hip_bfloat16* __restrict__ Wthi,
                       __hip_bfloat16* __restrict__ Wtlo) {
  const int n = blockIdx.x;          // 0..191
  const int m = n >> 6;
  const int h = n & 63;
  const float* W = (m == 0) ? Wq : (m == 1) ? Wk : Wv;
  const int e0 = threadIdx.x * 4;    // 256 threads * 4 = 1024
#pragma unroll
  for (int j = 0; j < 4; ++j) {
    const float w = W[(e0 + j) * 64 + h];
    const __hip_bfloat16 hi = __float2bfloat16(w);
    Wthi[n * 1024 + e0 + j] = hi;
    Wtlo[n * 1024 + e0 + j] = __float2bfloat16(w - __bfloat162float(hi));
  }
}

// ---------------------------------------------------------------------------
// Kernel A v2: 512 blocks x 32 rows (2 blocks/CU; old 64-row version was
// LDS-capped at 1 block/CU with grid 256 -> 8.7% occupancy, latency-bound).
// Waves col-split: wave w owns j-groups {w, w+4, w+8} (q, k, v stripes), so
// lo-correction work (j<8) is balanced. Blo lives in REGISTERS (16 VGPR/wave
// double-buffered) instead of LDS -> block LDS 116KB -> 66KB -> 2 blocks/CU.
// ---------------------------------------------------------------------------
__global__ __launch_bounds__(256) void qkv_gemm(
    const float* __restrict__ x,
    const __hip_bfloat16* __restrict__ Wthi, const __hip_bfloat16* __restrict__ Wtlo,
    __hip_bfloat16* __restrict__ qhi, __hip_bfloat16* __restrict__ qlo,
    __hip_bfloat16* __restrict__ khi, __hip_bfloat16* __restrict__ klo,
    __hip_bfloat16* __restrict__ vT) {
  __shared__ __hip_bfloat16 Ahi[2][32 * 72];
  __shared__ __hip_bfloat16 Alo[2][32 * 72];
  __shared__ __hip_bfloat16 Bhi[2][192 * 64];

  const int tid  = threadIdx.x;
  const int wave = tid >> 6;
  const int lane = tid & 63;
  const int row0 = blockIdx.x * 32;
  const int l15 = lane & 15, l4 = lane >> 4;

  const int lr = tid >> 3;           // 0..31 (row in strip)
  const int le = (tid & 7) * 8;      // 0..56 (col, floats)
  const float* xrow = x + (row0 + lr) * 1024 + le;

  f32x4 acc[2][3];
#pragma unroll
  for (int m = 0; m < 2; ++m)
#pragma unroll
    for (int j = 0; j < 3; ++j) acc[m][j] = f32x4{0.f, 0.f, 0.f, 0.f};

  // wave w stages only its own j-groups of Bhi (6 quads: 2 per j-group)
  auto issue_Bhi = [&](int c, int buf) {
    const int g = (lane & 7) ^ ((lane >> 3) & 7);
#pragma unroll
    for (int s = 0; s < 3; ++s) {
      const int j = wave + s * 4;
#pragma unroll
      for (int qh = 0; qh < 2; ++qh) {
        const int qq = j * 2 + qh;
        const int n  = qq * 8 + (lane >> 3);
        gload_lds16(Wthi + n * 1024 + c * 64 + g * 8, &Bhi[buf][qq * 512]);
      }
    }
  };
  // lo-correction B frags straight to registers (j=w and j=w+4, both < 8)
  auto load_Blo = [&](int c, short8* bl) {
#pragma unroll
    for (int jj = 0; jj < 2; ++jj) {
      const int j = wave + jj * 4;
      const __hip_bfloat16* p = Wtlo + (j * 16 + l15) * 1024 + c * 64;
      bl[jj * 2]     = *(const short8*)(p + l4 * 8);
      bl[jj * 2 + 1] = *(const short8*)(p + 32 + l4 * 8);
    }
  };
  auto write_A = [&](int buf, const f32x4* xr) {
    short8 h0, l0;
    const float* xf = (const float*)xr;
#pragma unroll
    for (int j = 0; j < 8; ++j) {
      const float v = xf[j];
      const short h = f2bf(v);
      h0[j] = h;
      l0[j] = f2bf(v - bf2f(h));
    }
    *(short8*)&Ahi[buf][lr * 72 + le] = h0;
    *(short8*)&Alo[buf][lr * 72 + le] = l0;
  };
  auto compute = [&](int buf, const short8* bl) {
#pragma unroll
    for (int m = 0; m < 2; ++m) {
      const int tr = m * 16 + l15;
      short8 ah0 = *(const short8*)&Ahi[buf][tr * 72 + l4 * 8];
      short8 ah1 = *(const short8*)&Ahi[buf][tr * 72 + 32 + l4 * 8];
      short8 al0 = *(const short8*)&Alo[buf][tr * 72 + l4 * 8];
      short8 al1 = *(const short8*)&Alo[buf][tr * 72 + 32 + l4 * 8];
#pragma unroll
      for (int jj = 0; jj < 3; ++jj) {
        const int j  = (jj < 2) ? (wave + jj * 4) : (wave + 8);
        const int n  = j * 16 + l15;
        const int o0 = ((l4)     ^ (n & 7)) * 8;
        const int o1 = ((4 + l4) ^ (n & 7)) * 8;
        short8 bh0 = *(const short8*)&Bhi[buf][n * 64 + o0];
        short8 bh1 = *(const short8*)&Bhi[buf][n * 64 + o1];
        acc[m][jj] = mfma_16x16x32(ah0, bh0, acc[m][jj]);
        acc[m][jj] = mfma_16x16x32(ah1, bh1, acc[m][jj]);
        if (jj < 2) {
          acc[m][jj] = mfma_16x16x32(ah0, bl[jj * 2],     acc[m][jj]);
          acc[m][jj] = mfma_16x16x32(ah1, bl[jj * 2 + 1], acc[m][jj]);
          acc[m][jj] = mfma_16x16x32(al0, bh0, acc[m][jj]);
          acc[m][jj] = mfma_16x16x32(al1, bh1, acc[m][jj]);
        }
      }
    }
  };

  f32x4 xr[2], xn[2];
  {
    const f32x4* p = (const f32x4*)xrow;
    xr[0] = p[0]; xr[1] = p[1];
  }
  short8 blc[4], bln[4];
  issue_Bhi(0, 0);
  load_Blo(0, blc);
  __builtin_amdgcn_s_waitcnt(0);
  write_A(0, xr);
  __syncthreads();

  for (int c = 0; c < 16; ++c) {
    const int p = c & 1;
    if (c < 15) {
      const f32x4* pp = (const f32x4*)(xrow + (c + 1) * 64);
      xn[0] = pp[0]; xn[1] = pp[1];
      issue_Bhi(c + 1, p ^ 1);
      load_Blo(c + 1, bln);
    }
    compute(p, blc);
    if (c < 15) {
      __builtin_amdgcn_s_waitcnt(0);
      write_A(p ^ 1, xn);
#pragma unroll
      for (int q = 0; q < 4; ++q) blc[q] = bln[q];
    }
    __syncthreads();
  }

  // Epilogue: wave w wrote cols w*16+l15 of q (jj=0), k (jj=1), v (jj=2)
  const int hcol = wave * 16 + l15;
#pragma unroll
  for (int jj = 0; jj < 3; ++jj) {
#pragma unroll
    for (int m = 0; m < 2; ++m) {
#pragma unroll
      for (int r = 0; r < 4; ++r) {
        const int trow = row0 + m * 16 + l4 * 4 + r;
        const float val = acc[m][jj][r];
        if (jj == 0) {
          const __hip_bfloat16 hi = __float2bfloat16(val);
          qhi[trow * 64 + hcol] = hi;
          qlo[trow * 64 + hcol] = __float2bfloat16(val - __bfloat162float(hi));
        } else if (jj == 1) {
          const __hip_bfloat16 hi = __float2bfloat16(val);
          khi[trow * 64 + hcol] = hi;
          klo[trow * 64 + hcol] = __float2bfloat16(val - __bfloat162float(hi));
        } else {
          const int bb = trow >> 11, tl = trow & 2047;
          vT[(bb * 64 + hcol) * 2048 + tl] = __float2bfloat16(val);
        }
      }
    }
  }
}

// ---------------------------------------------------------------------------
// Kernel B v7: 16-row strips -> grid 1024 (4 blocks/CU, 16 waves/CU; v6 was
// grid-capped at 2 blocks/CU = 12% occupancy, latency-bound: MfmaUtil 7%).
// Per-wave state halves (1 m-tile): Q 16 VGPR, acc 16 -> fits 128-VGPR cap
// (launch_bounds(256,4)). K frags loaded per-j inside the loop (keeps peak
// pressure low); fully-masked diagonal j-groups skip their K loads.
// ---------------------------------------------------------------------------
__global__ __launch_bounds__(256, 4) void attn(
    const __hip_bfloat16* __restrict__ qhi, const __hip_bfloat16* __restrict__ qlo,
    const __hip_bfloat16* __restrict__ khi, const __hip_bfloat16* __restrict__ klo,
    const __hip_bfloat16* __restrict__ vT, float* __restrict__ out) {
  __shared__ __hip_bfloat16 Psm[4][16 * 72];  // per-wave P transpose
  __shared__ float Osm[4][16][65];            // per-wave partial O (fp32)
  __shared__ float Msm[4][16];
  __shared__ float Lsm[4][16];

  const int tid  = threadIdx.x;
  const int wave = tid >> 6;
  const int lane = tid & 63;
  const int l15 = lane & 15, l4 = lane >> 4;

  const int b  = blockIdx.x & 7;             // XCD-local batch
  const int ss = 127 - (blockIdx.x >> 3);    // 16-row strip, big-work first
  const int t0 = ss * 16;
  const int ntiles = (ss >> 2) + 1;          // causal 64-key tiles

  // ---- Q A-frags, hi+lo (16 VGPRs) ----
  const __hip_bfloat16* qph = qhi + (b * 2048 + t0 + l15) * 64;
  const __hip_bfloat16* qpl = qlo + (b * 2048 + t0 + l15) * 64;
  const short8 qh0 = *(const short8*)(qph + l4 * 8);
  const short8 qh1 = *(const short8*)(qph + 32 + l4 * 8);
  const short8 ql0 = *(const short8*)(qpl + l4 * 8);
  const short8 ql1 = *(const short8*)(qpl + 32 + l4 * 8);

  f32x4 acc[4];
#pragma unroll
  for (int j = 0; j < 4; ++j) acc[j] = f32x4{0.f, 0.f, 0.f, 0.f};
  float m_[4], l_[4];
#pragma unroll
  for (int r = 0; r < 4; ++r) { m_[r] = -1e30f; l_[r] = 0.f; }

  const __hip_bfloat16* kbase_h = khi + (size_t)b * 2048 * 64;
  const __hip_bfloat16* kbase_l = klo + (size_t)b * 2048 * 64;
  const __hip_bfloat16* vbase   = vT + (size_t)b * 64 * 2048;

  // ---- K-loop: wave takes tiles wave, wave+4, ... ----
  for (int kt = wave; kt < ntiles; kt += 4) {
    const int k0 = kt << 6;
    const bool diag = (kt == ntiles - 1);

    f32x4 s_[4];
#pragma unroll
    for (int j = 0; j < 4; ++j) {
      if (diag && (k0 + j * 16) > (t0 + 15)) {  // fully masked group: skip loads
        s_[j] = f32x4{-1e30f, -1e30f, -1e30f, -1e30f};
      } else {
        const __hip_bfloat16* kph = kbase_h + (k0 + j * 16 + l15) * 64;
        const __hip_bfloat16* kpl = kbase_l + (k0 + j * 16 + l15) * 64;
        const short8 kh0 = *(const short8*)(kph + l4 * 8);
        const short8 kh1 = *(const short8*)(kph + 32 + l4 * 8);
        const short8 kl0 = *(const short8*)(kpl + l4 * 8);
        const short8 kl1 = *(const short8*)(kpl + 32 + l4 * 8);
        f32x4 z = f32x4{0.f, 0.f, 0.f, 0.f};
        z = mfma_16x16x32(qh0, kh0, z);
        z = mfma_16x16x32(qh1, kh1, z);
        z = mfma_16x16x32(qh0, kl0, z);
        z = mfma_16x16x32(qh1, kl1, z);
        z = mfma_16x16x32(ql0, kh0, z);
        z = mfma_16x16x32(ql1, kh1, z);
        s_[j] = z;
      }
    }
    if (diag) {   // partial mask where key > row
#pragma unroll
      for (int j = 0; j < 4; ++j) {
        const int key = k0 + j * 16 + l15;
#pragma unroll
        for (int r = 0; r < 4; ++r) {
          const int row = t0 + l4 * 4 + r;
          if (key > row) s_[j][r] = -1e30f;
        }
      }
    }

    // online softmax (4 rows/lane; reduce across 16-lane col groups)
    float mx[4], rs[4], al[4];
#pragma unroll
    for (int r = 0; r < 4; ++r)
      mx[r] = fmaxf(fmaxf(s_[0][r], s_[1][r]), fmaxf(s_[2][r], s_[3][r]));
    for (int off = 1; off < 16; off <<= 1) {
#pragma unroll
      for (int r = 0; r < 4; ++r) mx[r] = fmaxf(mx[r], __shfl_xor(mx[r], off));
    }
#pragma unroll
    for (int r = 0; r < 4; ++r) {
      const float mn = fmaxf(m_[r], mx[r]);
      al[r] = __expf(m_[r] - mn);
      m_[r] = mn;
      rs[r] = 0.f;
    }
#pragma unroll
    for (int j = 0; j < 4; ++j) {
#pragma unroll
      for (int r = 0; r < 4; ++r) {
        const float pv = __expf(s_[j][r] - m_[r]);
        s_[j][r] = pv;
        rs[r] += pv;
      }
    }
    for (int off = 1; off < 16; off <<= 1) {
#pragma unroll
      for (int r = 0; r < 4; ++r) rs[r] += __shfl_xor(rs[r], off);
    }
#pragma unroll
    for (int r = 0; r < 4; ++r) l_[r] = l_[r] * al[r] + rs[r];
#pragma unroll
    for (int j = 0; j < 4; ++j)
#pragma unroll
      for (int r = 0; r < 4; ++r) acc[j][r] *= al[r];

    // P (C-layout) -> per-wave LDS buffer
#pragma unroll
    for (int j = 0; j < 4; ++j)
#pragma unroll
      for (int r = 0; r < 4; ++r)
        Psm[wave][(l4 * 4 + r) * 72 + j * 16 + l15] = __float2bfloat16(s_[j][r]);

    // ---- V frags (stay in flight across the lgkm-only wait) ----
    short8 vf0[4], vf1[4];
#pragma unroll
    for (int j = 0; j < 4; ++j) {
      const __hip_bfloat16* vp = vbase + (j * 16 + l15) * 2048 + k0;
      vf0[j] = *(const short8*)(vp + l4 * 8);
      vf1[j] = *(const short8*)(vp + 32 + l4 * 8);
    }

    WAIT_LGKM0();   // P LDS writes visible to same wave; vmcnt untouched

    // ---- O += P V ----
    const short8 pf0 = *(const short8*)&Psm[wave][l15 * 72 + l4 * 8];
    const short8 pf1 = *(const short8*)&Psm[wave][l15 * 72 + 32 + l4 * 8];
#pragma unroll
    for (int j = 0; j < 4; ++j) {
      acc[j] = mfma_16x16x32(pf0, vf0[j], acc[j]);
      acc[j] = mfma_16x16x32(pf1, vf1[j], acc[j]);
    }
  }

  // ---- per-wave partials into LDS (fp32) ----
#pragma unroll
  for (int j = 0; j < 4; ++j)
#pragma unroll
    for (int r = 0; r < 4; ++r)
      Osm[wave][l4 * 4 + r][j * 16 + l15] = acc[j][r];
  if (l15 == 0) {
#pragma unroll
    for (int r = 0; r < 4; ++r) {
      Msm[wave][l4 * 4 + r] = m_[r];
      Lsm[wave][l4 * 4 + r] = l_[r];
    }
  }
  __syncthreads();

  // ---- cross-wave merge: wave handles rows [wave*4, +4), lane = h ----
#pragma unroll
  for (int rr = 0; rr < 4; ++rr) {
    const int row = wave * 4 + rr;
    float M = fmaxf(fmaxf(Msm[0][row], Msm[1][row]),
                    fmaxf(Msm[2][row], Msm[3][row]));
    float L = 0.f, O = 0.f;
#pragma unroll
    for (int w2 = 0; w2 < 4; ++w2) {
      const float a = __expf(Msm[w2][row] - M);
      L += a * Lsm[w2][row];
      O += a * Osm[w2][row][lane];
    }
    out[(b * 2048 + t0 + row) * 64 + lane] = O / L;
  }
}

// ---------------------------------------------------------------------------
extern "C" void kernel_launch(void* const* d_in, const int* in_sizes, int n_in,
                              void* d_out, int out_size, void* d_ws, size_t ws_size,
                              hipStream_t stream) {
  const float* x  = (const float*)d_in[0];
  const float* Wq = (const float*)d_in[1];
  const float* Wk = (const float*)d_in[2];
  const float* Wv = (const float*)d_in[3];
  float* out = (float*)d_out;

  char* ws = (char*)d_ws;
  __hip_bfloat16* Wthi = (__hip_bfloat16*)ws;                   // 384 KB
  __hip_bfloat16* Wtlo = (__hip_bfloat16*)(ws + 393216);        // 384 KB
  __hip_bfloat16* qhi  = (__hip_bfloat16*)(ws + 786432);        // 2 MB each
  __hip_bfloat16* qlo  = (__hip_bfloat16*)(ws + 786432 + 1 * 2097152);
  __hip_bfloat16* khi  = (__hip_bfloat16*)(ws + 786432 + 2 * 2097152);
  __hip_bfloat16* klo  = (__hip_bfloat16*)(ws + 786432 + 3 * 2097152);
  __hip_bfloat16* vT   = (__hip_bfloat16*)(ws + 786432 + 4 * 2097152);

  prep_w<<<192, 256, 0, stream>>>(Wq, Wk, Wv, Wthi, Wtlo);
  qkv_gemm<<<512, 256, 0, stream>>>(x, Wthi, Wtlo, qhi, qlo, khi, klo, vT);
  attn<<<1024, 256, 0, stream>>>(qhi, qlo, khi, klo, vT, out);
}